// Round 19
// baseline (182.520 us; speedup 1.0000x reference)
//
#include <hip/hip_runtime.h>
#include <hip/hip_bf16.h>

// Float inputs/outputs are FP32 (established r14/r15). Intermediates are
// packed-bf16 (u32/uint2). h1/a1 stored PRE-SCALED by dis[src] (r17).
// r18: aggpre fused into gemm2s. r19: GEMM inner loops read activations as
// float4 (4-k chunks) -> all-b128 LDS traffic, FMA-bound.

#define BB 128
#define NN 512
#define NODES (BB*NN)          // 65536
#define EE (BB*NN*8)           // 524288
#define EDGPG (NN*8)           // 4096 edges per graph (graph-contiguous)
#define F_IN 128
#define H1 64
#define H2 128
#define NC 10
#define KSEL 410
#define EPG (NN*8 + NN)        // 4608 adj entries per graph
#define TOT_ADJ (EE + NODES)   // 589824

typedef unsigned short u16;
typedef unsigned int   u32;

static __device__ __forceinline__ float lo2f(u32 u){ return __uint_as_float(u << 16); }
static __device__ __forceinline__ float hi2f(u32 u){ return __uint_as_float(u & 0xffff0000u); }
static __device__ __forceinline__ u16 f2b(float f){
    __hip_bfloat16 h = __float2bfloat16(f);   // RNE
    return *reinterpret_cast<u16*>(&h);
}
static __device__ __forceinline__ u32 packbf(float a, float b){
    return (u32)f2b(a) | ((u32)f2b(b) << 16);
}

// edge_index may arrive as int64 (odd 32-bit words all zero) or int32.
static __device__ __forceinline__ bool ei_is_i64(const int* __restrict__ ei){
    return ((ei[1] | ei[3] | ei[5] | ei[7]) == 0);
}
static __device__ __forceinline__ int ld_src(const int* __restrict__ ei, int e, bool w64){
    return w64 ? ei[2*e] : ei[e];
}
static __device__ __forceinline__ int ld_dst(const int* __restrict__ ei, int e, bool w64){
    return w64 ? ei[2*(EE + e)] : ei[EE + e];
}

// ---- CSR build: one block per graph, count+scan+fill all in LDS ----
__global__ __launch_bounds__(512) void k_build(const int* __restrict__ ei,
                                               int* __restrict__ row_start,
                                               int* __restrict__ cnt_g,
                                               float* __restrict__ dis,
                                               int* __restrict__ adj){
    __shared__ int cnt[NN];
    __shared__ int sh[NN];
    __shared__ int cur[NN];
    bool w64 = ei_is_i64(ei);
    int b = blockIdx.x, t = threadIdx.x;
    cnt[t] = 0;
    __syncthreads();
    int e0 = b*EDGPG;
    for (int i = t; i < EDGPG; i += 512){
        int d = (ld_dst(ei, e0 + i, w64) - b*NN) & (NN - 1);   // local id (clamped)
        atomicAdd(&cnt[d], 1);
    }
    __syncthreads();
    int tot = cnt[t] + 1;          // +1 self loop
    sh[t] = tot;
    __syncthreads();
    for (int off = 1; off < NN; off <<= 1){
        int v = (t >= off) ? sh[t-off] : 0;
        __syncthreads();
        sh[t] += v;
        __syncthreads();
    }
    int rs_local = sh[t] - tot;    // exclusive scan
    row_start[b*NN + t] = b*EPG + rs_local;
    cnt_g[b*NN + t]     = tot - 1;
    dis[b*NN + t]       = rsqrtf((float)tot);
    cur[t] = rs_local;
    __syncthreads();
    {   // self loop first
        int p = atomicAdd(&cur[t], 1);
        adj[b*EPG + p] = b*NN + t;
    }
    for (int i = t; i < EDGPG; i += 512){
        int d = (ld_dst(ei, e0 + i, w64) - b*NN) & (NN - 1);
        int s = ld_src(ei, e0 + i, w64) & (NODES - 1);         // global src id
        int p = atomicAdd(&cur[d], 1);
        adj[b*EPG + p] = s;
    }
}

// h1' = dis[node] * (x @ W1): 64 nodes x 64 cols per block, 4x4 tile/thread,
// k-split halves, float4 staging, row-major x tile, ALL-float4 inner loop.
#define G1NODES 64
#define XPAD 68
__global__ __launch_bounds__(256) void k_gemm1(const float* __restrict__ x,
                                               const float* __restrict__ W1,
                                               const float* __restrict__ dis,
                                               u32* __restrict__ h1u){
    __shared__ __align__(16) float Ws[64*H1];          // 16 KB (one k-half)
    __shared__ __align__(16) float xs[G1NODES*XPAD];   // 17.4 KB
    int t = threadIdx.x;
    int node0 = blockIdx.x*G1NODES;
    int tc = t & 15, tr = t >> 4;
    int j0 = tc*4, n0 = tr*4;
    float acc[4][4] = {};
    for (int half = 0; half < 2; ++half){
        const float4* Wv = (const float4*)(W1 + half*4096);
        for (int i = t; i < 1024; i += 256)
            *(float4*)&Ws[i*4] = Wv[i];
        for (int i = t; i < 1024; i += 256){
            int node = i >> 4, c = i & 15;
            float4 v = *(const float4*)(x + (size_t)(node0 + node)*F_IN + half*64 + c*4);
            *(float4*)&xs[node*XPAD + c*4] = v;
        }
        __syncthreads();
        #pragma unroll 4
        for (int k4 = 0; k4 < 64; k4 += 4){
            float4 xv0 = *(const float4*)&xs[(n0+0)*XPAD + k4];
            float4 xv1 = *(const float4*)&xs[(n0+1)*XPAD + k4];
            float4 xv2 = *(const float4*)&xs[(n0+2)*XPAD + k4];
            float4 xv3 = *(const float4*)&xs[(n0+3)*XPAD + k4];
            float4 wv0 = *(const float4*)&Ws[(k4+0)*H1 + j0];
            float4 wv1 = *(const float4*)&Ws[(k4+1)*H1 + j0];
            float4 wv2 = *(const float4*)&Ws[(k4+2)*H1 + j0];
            float4 wv3 = *(const float4*)&Ws[(k4+3)*H1 + j0];
            // strict k-order accumulation (bit-identical to scalar loop)
            acc[0][0] += xv0.x*wv0.x; acc[0][0] += xv0.y*wv1.x; acc[0][0] += xv0.z*wv2.x; acc[0][0] += xv0.w*wv3.x;
            acc[0][1] += xv0.x*wv0.y; acc[0][1] += xv0.y*wv1.y; acc[0][1] += xv0.z*wv2.y; acc[0][1] += xv0.w*wv3.y;
            acc[0][2] += xv0.x*wv0.z; acc[0][2] += xv0.y*wv1.z; acc[0][2] += xv0.z*wv2.z; acc[0][2] += xv0.w*wv3.z;
            acc[0][3] += xv0.x*wv0.w; acc[0][3] += xv0.y*wv1.w; acc[0][3] += xv0.z*wv2.w; acc[0][3] += xv0.w*wv3.w;
            acc[1][0] += xv1.x*wv0.x; acc[1][0] += xv1.y*wv1.x; acc[1][0] += xv1.z*wv2.x; acc[1][0] += xv1.w*wv3.x;
            acc[1][1] += xv1.x*wv0.y; acc[1][1] += xv1.y*wv1.y; acc[1][1] += xv1.z*wv2.y; acc[1][1] += xv1.w*wv3.y;
            acc[1][2] += xv1.x*wv0.z; acc[1][2] += xv1.y*wv1.z; acc[1][2] += xv1.z*wv2.z; acc[1][2] += xv1.w*wv3.z;
            acc[1][3] += xv1.x*wv0.w; acc[1][3] += xv1.y*wv1.w; acc[1][3] += xv1.z*wv2.w; acc[1][3] += xv1.w*wv3.w;
            acc[2][0] += xv2.x*wv0.x; acc[2][0] += xv2.y*wv1.x; acc[2][0] += xv2.z*wv2.x; acc[2][0] += xv2.w*wv3.x;
            acc[2][1] += xv2.x*wv0.y; acc[2][1] += xv2.y*wv1.y; acc[2][1] += xv2.z*wv2.y; acc[2][1] += xv2.w*wv3.y;
            acc[2][2] += xv2.x*wv0.z; acc[2][2] += xv2.y*wv1.z; acc[2][2] += xv2.z*wv2.z; acc[2][2] += xv2.w*wv3.z;
            acc[2][3] += xv2.x*wv0.w; acc[2][3] += xv2.y*wv1.w; acc[2][3] += xv2.z*wv2.w; acc[2][3] += xv2.w*wv3.w;
            acc[3][0] += xv3.x*wv0.x; acc[3][0] += xv3.y*wv1.x; acc[3][0] += xv3.z*wv2.x; acc[3][0] += xv3.w*wv3.x;
            acc[3][1] += xv3.x*wv0.y; acc[3][1] += xv3.y*wv1.y; acc[3][1] += xv3.z*wv2.y; acc[3][1] += xv3.w*wv3.y;
            acc[3][2] += xv3.x*wv0.z; acc[3][2] += xv3.y*wv1.z; acc[3][2] += xv3.z*wv2.z; acc[3][2] += xv3.w*wv3.z;
            acc[3][3] += xv3.x*wv0.w; acc[3][3] += xv3.y*wv1.w; acc[3][3] += xv3.z*wv2.w; acc[3][3] += xv3.w*wv3.w;
        }
        __syncthreads();
    }
    #pragma unroll
    for (int i = 0; i < 4; ++i){
        float dn = dis[node0 + n0 + i];
        size_t base = (size_t)(node0 + n0 + i)*32 + tc*2;
        h1u[base]     = packbf(dn*acc[i][0], dn*acc[i][1]);
        h1u[base + 1] = packbf(dn*acc[i][2], dn*acc[i][3]);
    }
}

// a1' = dis[node] * relu(dis[node]*sum h1'[s] + b1): 16 nodes/block,
// 16 lanes/node, 4 feats/lane via uint2 gathers.
__global__ __launch_bounds__(256) void k_agg1(const uint2* __restrict__ h1v,
                                              const int* __restrict__ row_start,
                                              const int* __restrict__ cnt,
                                              const int* __restrict__ adj,
                                              const float* __restrict__ dis,
                                              const float4* __restrict__ b1v,
                                              uint2* __restrict__ a1v){
    int t = threadIdx.x;
    int node = blockIdx.x*16 + (t >> 4);
    int fl = t & 15;
    int rs = row_start[node];
    int deg = cnt[node] + 1; if (deg > EPG) deg = EPG;
    int pe = rs + deg;
    float a0[4] = {}, a1r[4] = {}, a2r[4] = {}, a3r[4] = {};
    int p = rs;
    for (; p + 4 <= pe; p += 4){
        int s0 = adj[p], s1 = adj[p+1], s2 = adj[p+2], s3 = adj[p+3];
        uint2 v0 = h1v[s0*16 + fl];
        uint2 v1 = h1v[s1*16 + fl];
        uint2 v2 = h1v[s2*16 + fl];
        uint2 v3 = h1v[s3*16 + fl];
        a0[0] += lo2f(v0.x); a0[1] += hi2f(v0.x); a0[2] += lo2f(v0.y); a0[3] += hi2f(v0.y);
        a1r[0] += lo2f(v1.x); a1r[1] += hi2f(v1.x); a1r[2] += lo2f(v1.y); a1r[3] += hi2f(v1.y);
        a2r[0] += lo2f(v2.x); a2r[1] += hi2f(v2.x); a2r[2] += lo2f(v2.y); a2r[3] += hi2f(v2.y);
        a3r[0] += lo2f(v3.x); a3r[1] += hi2f(v3.x); a3r[2] += lo2f(v3.y); a3r[3] += hi2f(v3.y);
    }
    for (; p < pe; ++p){
        int s = adj[p];
        uint2 v = h1v[s*16 + fl];
        a0[0] += lo2f(v.x); a0[1] += hi2f(v.x); a0[2] += lo2f(v.y); a0[3] += hi2f(v.y);
    }
    float r0 = (a0[0] + a1r[0]) + (a2r[0] + a3r[0]);
    float r1 = (a0[1] + a1r[1]) + (a2r[1] + a3r[1]);
    float r2 = (a0[2] + a1r[2]) + (a2r[2] + a3r[2]);
    float r3 = (a0[3] + a1r[3]) + (a2r[3] + a3r[3]);
    float dn = dis[node];
    float4 bb = b1v[fl];
    float w0 = dn*r0 + bb.x; w0 = w0 > 0.f ? w0 : 0.f;
    float w1 = dn*r1 + bb.y; w1 = w1 > 0.f ? w1 : 0.f;
    float w2 = dn*r2 + bb.z; w2 = w2 > 0.f ? w2 : 0.f;
    float w3 = dn*r3 + bb.w; w3 = w3 > 0.f ? w3 : 0.f;
    a1v[node*16 + fl] = make_uint2(packbf(dn*w0, dn*w1), packbf(dn*w2, dn*w3));
}

// FUSED: agg (gather of pre-scaled a1') built directly in LDS (f32), then
// a2 = relu(agg @ W2 + b2) + raw score = a2 . pw. 32 nodes x 128 cols/block.
#define G2NODES 32
#define APAD 68
__global__ __launch_bounds__(256) void k_gemm2s(const uint2* __restrict__ a1v,
                                                const int* __restrict__ row_start,
                                                const int* __restrict__ cnt,
                                                const int* __restrict__ adj,
                                                const float* __restrict__ dis,
                                                const float* __restrict__ W2,
                                                const float* __restrict__ b2,
                                                const float* __restrict__ pw,
                                                u32* __restrict__ a2u,
                                                float* __restrict__ score){
    __shared__ __align__(16) float Ws[32*H2];          // 16 KB (one k-half)
    __shared__ __align__(16) float as[G2NODES*APAD];   // 8.7 KB (full k, f32)
    __shared__ float pws[H2];
    int t = threadIdx.x;
    int node0 = blockIdx.x*G2NODES;
    if (t < H2) pws[t] = pw[t];
    // fused aggpre: 16 lanes/node, 2 passes x 16 nodes
    {
        int fl = t & 15, ng = t >> 4;
        for (int pass = 0; pass < 2; ++pass){
            int nl = ng + pass*16;
            int node = node0 + nl;
            int rs = row_start[node];
            int deg = cnt[node] + 1; if (deg > EPG) deg = EPG;
            int pe = rs + deg;
            float a0[4] = {}, a1r[4] = {}, a2r[4] = {}, a3r[4] = {};
            int p = rs;
            for (; p + 4 <= pe; p += 4){
                int s0 = adj[p], s1 = adj[p+1], s2 = adj[p+2], s3 = adj[p+3];
                uint2 v0 = a1v[s0*16 + fl];
                uint2 v1 = a1v[s1*16 + fl];
                uint2 v2 = a1v[s2*16 + fl];
                uint2 v3 = a1v[s3*16 + fl];
                a0[0] += lo2f(v0.x); a0[1] += hi2f(v0.x); a0[2] += lo2f(v0.y); a0[3] += hi2f(v0.y);
                a1r[0] += lo2f(v1.x); a1r[1] += hi2f(v1.x); a1r[2] += lo2f(v1.y); a1r[3] += hi2f(v1.y);
                a2r[0] += lo2f(v2.x); a2r[1] += hi2f(v2.x); a2r[2] += lo2f(v2.y); a2r[3] += hi2f(v2.y);
                a3r[0] += lo2f(v3.x); a3r[1] += hi2f(v3.x); a3r[2] += lo2f(v3.y); a3r[3] += hi2f(v3.y);
            }
            for (; p < pe; ++p){
                int s = adj[p];
                uint2 v = a1v[s*16 + fl];
                a0[0] += lo2f(v.x); a0[1] += hi2f(v.x); a0[2] += lo2f(v.y); a0[3] += hi2f(v.y);
            }
            float dn = dis[node];
            float* dst = &as[nl*APAD + 4*fl];
            dst[0] = dn*((a0[0] + a1r[0]) + (a2r[0] + a3r[0]));
            dst[1] = dn*((a0[1] + a1r[1]) + (a2r[1] + a3r[1]));
            dst[2] = dn*((a0[2] + a1r[2]) + (a2r[2] + a3r[2]));
            dst[3] = dn*((a0[3] + a1r[3]) + (a2r[3] + a3r[3]));
        }
    }
    int tc = t & 31, tr = t >> 5;
    int j0 = tc*4, n0 = tr*4;
    float acc[4][4] = {};
    for (int half = 0; half < 2; ++half){
        const float4* Wv = (const float4*)(W2 + half*4096);
        for (int i = t; i < 1024; i += 256)
            *(float4*)&Ws[i*4] = Wv[i];
        __syncthreads();   // first pass also covers as + pws
        int kb = half*32;
        #pragma unroll 4
        for (int k4 = 0; k4 < 32; k4 += 4){
            float4 xv0 = *(const float4*)&as[(n0+0)*APAD + kb + k4];
            float4 xv1 = *(const float4*)&as[(n0+1)*APAD + kb + k4];
            float4 xv2 = *(const float4*)&as[(n0+2)*APAD + kb + k4];
            float4 xv3 = *(const float4*)&as[(n0+3)*APAD + kb + k4];
            float4 wv0 = *(const float4*)&Ws[(k4+0)*H2 + j0];
            float4 wv1 = *(const float4*)&Ws[(k4+1)*H2 + j0];
            float4 wv2 = *(const float4*)&Ws[(k4+2)*H2 + j0];
            float4 wv3 = *(const float4*)&Ws[(k4+3)*H2 + j0];
            acc[0][0] += xv0.x*wv0.x; acc[0][0] += xv0.y*wv1.x; acc[0][0] += xv0.z*wv2.x; acc[0][0] += xv0.w*wv3.x;
            acc[0][1] += xv0.x*wv0.y; acc[0][1] += xv0.y*wv1.y; acc[0][1] += xv0.z*wv2.y; acc[0][1] += xv0.w*wv3.y;
            acc[0][2] += xv0.x*wv0.z; acc[0][2] += xv0.y*wv1.z; acc[0][2] += xv0.z*wv2.z; acc[0][2] += xv0.w*wv3.z;
            acc[0][3] += xv0.x*wv0.w; acc[0][3] += xv0.y*wv1.w; acc[0][3] += xv0.z*wv2.w; acc[0][3] += xv0.w*wv3.w;
            acc[1][0] += xv1.x*wv0.x; acc[1][0] += xv1.y*wv1.x; acc[1][0] += xv1.z*wv2.x; acc[1][0] += xv1.w*wv3.x;
            acc[1][1] += xv1.x*wv0.y; acc[1][1] += xv1.y*wv1.y; acc[1][1] += xv1.z*wv2.y; acc[1][1] += xv1.w*wv3.y;
            acc[1][2] += xv1.x*wv0.z; acc[1][2] += xv1.y*wv1.z; acc[1][2] += xv1.z*wv2.z; acc[1][2] += xv1.w*wv3.z;
            acc[1][3] += xv1.x*wv0.w; acc[1][3] += xv1.y*wv1.w; acc[1][3] += xv1.z*wv2.w; acc[1][3] += xv1.w*wv3.w;
            acc[2][0] += xv2.x*wv0.x; acc[2][0] += xv2.y*wv1.x; acc[2][0] += xv2.z*wv2.x; acc[2][0] += xv2.w*wv3.x;
            acc[2][1] += xv2.x*wv0.y; acc[2][1] += xv2.y*wv1.y; acc[2][1] += xv2.z*wv2.y; acc[2][1] += xv2.w*wv3.y;
            acc[2][2] += xv2.x*wv0.z; acc[2][2] += xv2.y*wv1.z; acc[2][2] += xv2.z*wv2.z; acc[2][2] += xv2.w*wv3.z;
            acc[2][3] += xv2.x*wv0.w; acc[2][3] += xv2.y*wv1.w; acc[2][3] += xv2.z*wv2.w; acc[2][3] += xv2.w*wv3.w;
            acc[3][0] += xv3.x*wv0.x; acc[3][0] += xv3.y*wv1.x; acc[3][0] += xv3.z*wv2.x; acc[3][0] += xv3.w*wv3.x;
            acc[3][1] += xv3.x*wv0.y; acc[3][1] += xv3.y*wv1.y; acc[3][1] += xv3.z*wv2.y; acc[3][1] += xv3.w*wv3.y;
            acc[3][2] += xv3.x*wv0.z; acc[3][2] += xv3.y*wv1.z; acc[3][2] += xv3.z*wv2.z; acc[3][2] += xv3.w*wv3.z;
            acc[3][3] += xv3.x*wv0.w; acc[3][3] += xv3.y*wv1.w; acc[3][3] += xv3.z*wv2.w; acc[3][3] += xv3.w*wv3.w;
        }
        __syncthreads();
    }
    float p0 = pws[j0], p1 = pws[j0+1], p2 = pws[j0+2], p3 = pws[j0+3];
    float bj0 = b2[j0], bj1 = b2[j0+1], bj2 = b2[j0+2], bj3 = b2[j0+3];
    #pragma unroll
    for (int i = 0; i < 4; ++i){
        float v0 = acc[i][0] + bj0; v0 = v0 > 0.f ? v0 : 0.f;
        float v1 = acc[i][1] + bj1; v1 = v1 > 0.f ? v1 : 0.f;
        float v2 = acc[i][2] + bj2; v2 = v2 > 0.f ? v2 : 0.f;
        float v3 = acc[i][3] + bj3; v3 = v3 > 0.f ? v3 : 0.f;
        size_t base = (size_t)(node0 + n0 + i)*64 + tc*2;
        a2u[base]     = packbf(v0, v1);
        a2u[base + 1] = packbf(v2, v3);
        float sp = v0*p0 + v1*p1 + v2*p2 + v3*p3;
        sp += __shfl_xor(sp, 16, 32);
        sp += __shfl_xor(sp,  8, 32);
        sp += __shfl_xor(sp,  4, 32);
        sp += __shfl_xor(sp,  2, 32);
        sp += __shfl_xor(sp,  1, 32);
        if (tc == 0) score[node0 + n0 + i] = sp;   // raw (unscaled) dot
    }
}

// per graph: ||pw||^-1, top-K threshold (bitonic sort), branchless gated
// max-pool (uint2 loads, 4 feats/lane, 16 node-groups), FC (LDS-staged W),
// log_softmax. f32 out.
__global__ __launch_bounds__(512) void k_pool(const u32* __restrict__ a2u,
                                              const float* __restrict__ score,
                                              const float* __restrict__ pw,
                                              const float* __restrict__ fcW,
                                              const float* __restrict__ fcb,
                                              float* __restrict__ out){
    __shared__ float so[NN];
    __shared__ float ss[NN];
    __shared__ float th[NN];
    __shared__ float pm[16*H2];    // 8 KB
    __shared__ float gl[H2];
    __shared__ float fws[H2*NC];   // 5 KB
    __shared__ float lg[NC];
    __shared__ float red[3];
    int b = blockIdx.x, t = threadIdx.x;
    for (int i = t; i < H2*NC; i += 512) fws[i] = fcW[i];
    if (t < H2){ float v = pw[t]; gl[t] = v*v; }
    __syncthreads();
    if (t == 0){
        float s = 0.f;
        for (int i = 0; i < H2; ++i) s += gl[i];
        red[2] = rsqrtf(s);
    }
    __syncthreads();
    float pwinv = red[2];
    float sc = score[b*NN + t];                 // raw dot
    so[t] = sc; ss[t] = sc; th[t] = tanhf(sc*pwinv);
    __syncthreads();
    // bitonic sort descending (raw scores; positive scale preserves order)
    for (int k = 2; k <= NN; k <<= 1){
        for (int j = k >> 1; j > 0; j >>= 1){
            int ixj = t ^ j;
            if (ixj > t){
                float a = ss[t], c = ss[ixj];
                bool desc = ((t & k) == 0);
                bool sw = desc ? (a < c) : (a > c);
                if (sw){ ss[t] = c; ss[ixj] = a; }
            }
            __syncthreads();
        }
    }
    float thresh = ss[KSEL-1];
    float mask_t = (so[t] >= thresh) ? 0.f : -INFINITY;
    __syncthreads();
    so[t] = mask_t;
    __syncthreads();
    // gated max: lane tc handles feats {4tc..4tc+3} via uint2; group q: 32 nodes
    int tc = t & 31, q = t >> 5;
    const uint2* ap = (const uint2*)(a2u + (size_t)b*NN*64);
    float m0 = -INFINITY, m1 = -INFINITY, m2 = -INFINITY, m3 = -INFINITY;
    int nb = q*32;
    #pragma unroll 4
    for (int n = nb; n < nb + 32; ++n){
        uint2 v = ap[(size_t)n*32 + tc];
        float thn = th[n], son = so[n];
        m0 = fmaxf(m0, lo2f(v.x)*thn + son);
        m1 = fmaxf(m1, hi2f(v.x)*thn + son);
        m2 = fmaxf(m2, lo2f(v.y)*thn + son);
        m3 = fmaxf(m3, hi2f(v.y)*thn + son);
    }
    pm[q*H2 + 4*tc]     = m0;
    pm[q*H2 + 4*tc + 1] = m1;
    pm[q*H2 + 4*tc + 2] = m2;
    pm[q*H2 + 4*tc + 3] = m3;
    __syncthreads();
    if (t < H2){
        float g = pm[t];
        #pragma unroll
        for (int qq = 1; qq < 16; ++qq) g = fmaxf(g, pm[qq*H2 + t]);
        gl[t] = g;
    }
    __syncthreads();
    if (t < NC){
        float acc = fcb[t];
        for (int k2 = 0; k2 < H2; ++k2) acc += gl[k2]*fws[k2*NC + t];
        lg[t] = acc;
    }
    __syncthreads();
    if (t == 0){
        float mx = lg[0];
        for (int i = 1; i < NC; ++i) mx = fmaxf(mx, lg[i]);
        float s = 0.f;
        for (int i = 0; i < NC; ++i) s += expf(lg[i] - mx);
        red[0] = mx; red[1] = logf(s);
    }
    __syncthreads();
    if (t < NC) out[b*NC + t] = lg[t] - red[0] - red[1];
}

extern "C" void kernel_launch(void* const* d_in, const int* in_sizes, int n_in,
                              void* d_out, int out_size, void* d_ws, size_t ws_size,
                              hipStream_t stream) {
    const float* x   = (const float*)d_in[0];
    const int*   ei  = (const int*)d_in[1];
    // d_in[2] = batch (unused; batch = node / NN)
    const float* W1  = (const float*)d_in[3];
    const float* b1  = (const float*)d_in[4];
    const float* W2  = (const float*)d_in[5];
    const float* b2  = (const float*)d_in[6];
    const float* pw  = (const float*)d_in[7];
    const float* fcW = (const float*)d_in[8];
    const float* fcb = (const float*)d_in[9];

    char* ws = (char*)d_ws;
    int*   cnt       = (int*)(ws + 4096);       // 256KB -> 266240
    int*   row_start = (int*)(ws + 266240);     // -> 528384
    float* dis       = (float*)(ws + 528384);   // -> 790528
    float* score     = (float*)(ws + 790528);   // -> 1052672
    int*   adj       = (int*)(ws + 1052672);    // 589824 ints -> 3411968
    u32*   h1u       = (u32*)(ws + 4194304);    // 8MB -> 12582912
    u32*   a1u       = (u32*)(ws + 12582912);   // 8MB -> 20971520 (LIVE during gemm2s)
    u32*   a2u       = (u32*)(ws + 20971520);   // 16MB -> 37748736

    k_build<<<BB, 512, 0, stream>>>(ei, row_start, cnt, dis, adj);
    k_gemm1<<<NODES/G1NODES, 256, 0, stream>>>(x, W1, dis, h1u);
    k_agg1<<<NODES/16, 256, 0, stream>>>((const uint2*)h1u, row_start, cnt, adj, dis,
                                         (const float4*)b1, (uint2*)a1u);
    k_gemm2s<<<NODES/G2NODES, 256, 0, stream>>>((const uint2*)a1u, row_start, cnt, adj,
                                                dis, W2, b2, pw, a2u, score);
    k_pool<<<BB, 512, 0, stream>>>(a2u, score, pw, fcW, fcb, (float*)d_out);
}